// Round 2
// 422.182 us; speedup vs baseline: 1.0135x; 1.0135x over previous
//
#include <hip/hip_runtime.h>
#include <math.h>

// Problem dims
#define Mm 8
#define Bb 64
#define Ss 1024
#define Kk 256
#define Hh 8
#define HD 32
#define Ff 1024

typedef _Float16 f16x8 __attribute__((ext_vector_type(8)));
typedef float f32x4 __attribute__((ext_vector_type(4)));

// Workspace layout (float offsets), lifetimes disjoint where overlapped:
#define WS_Q      0u         // k1->k2; then FCP (fp16, k5->k6)
#define WS_U      131072u    // k2->k3, then GATES at 262144
#define WS_QDB    1179648u   // k2->k3
#define WS_SC     1183744u   // k3->k4a, then HPART (k7a->k7b)
#define WS_W      5378048u   // k4a->k5 (1048576 floats)
#define WS_H1P    6426624u   // fp16 frag-layout h1: k6->k6b/k7a (2M float units)
#define WS_FCP    0u
#define WS_GATES  262144u
#define WS_HPART  1183744u

__device__ __forceinline__ unsigned pk2(float a, float b) {
  union { unsigned u; _Float16 h[2]; } c;
  c.h[0] = (_Float16)a; c.h[1] = (_Float16)b;
  return c.u;
}

// ---------------------------------------------------------------------------
// K1: q = q0 @ Wq + bq        (M,B,K)
__global__ __launch_bounds__(256) void k1_qproj(
    const float* __restrict__ q0, const float* __restrict__ wq,
    const float* __restrict__ bq, float* __restrict__ qout) {
  __shared__ float q0s[8 * 260];
  const int m = blockIdx.x, b0 = blockIdx.y * 8, t = threadIdx.x;
#pragma unroll
  for (int j = 0; j < 8; ++j)
    q0s[j * 260 + t] = q0[(m * Bb + b0 + j) * Kk + t];
  __syncthreads();
  float acc[8];
  const float bias = bq[m * Kk + t];
#pragma unroll
  for (int j = 0; j < 8; ++j) acc[j] = bias;
  const float* wcol = wq + m * Kk * Kk + t;
  for (int k4 = 0; k4 < Kk / 4; ++k4) {
    const float w0 = wcol[(k4 * 4 + 0) * Kk];
    const float w1 = wcol[(k4 * 4 + 1) * Kk];
    const float w2 = wcol[(k4 * 4 + 2) * Kk];
    const float w3 = wcol[(k4 * 4 + 3) * Kk];
#pragma unroll
    for (int j = 0; j < 8; ++j) {
      const float4 qv = *(const float4*)&q0s[j * 260 + k4 * 4];
      acc[j] += qv.x * w0 + qv.y * w1 + qv.z * w2 + qv.w * w3;
    }
  }
#pragma unroll
  for (int j = 0; j < 8; ++j)
    qout[(m * Bb + b0 + j) * Kk + t] = acc[j];
}

// ---------------------------------------------------------------------------
// K2: u(m,b,h,k) = sum_d Wk[m,k,h*32+d] * q[m,b,h*32+d]
__global__ __launch_bounds__(256) void k2_uproj(
    const float* __restrict__ wk, const float* __restrict__ bk,
    const float* __restrict__ q, float* __restrict__ u,
    float* __restrict__ qdb) {
  __shared__ float qs[64 * 36];
  const int m = blockIdx.x, h = blockIdx.y, t = threadIdx.x;
#pragma unroll
  for (int p = 0; p < 8; ++p) {
    const int idx = p * 256 + t;
    const int d = idx & 31, b = idx >> 5;
    qs[b * 36 + d] = q[(m * Bb + b) * Kk + h * HD + d];
  }
  __syncthreads();
  float acc[64];
#pragma unroll
  for (int b = 0; b < 64; ++b) acc[b] = 0.f;
  const float* wrow = wk + (m * Kk + t) * Kk + h * HD;
#pragma unroll
  for (int d4 = 0; d4 < 8; ++d4) {
    const float4 w4 = *(const float4*)&wrow[d4 * 4];
#pragma unroll
    for (int b = 0; b < 64; ++b) {
      const float4 q4 = *(const float4*)&qs[b * 36 + d4 * 4];
      acc[b] += q4.x * w4.x + q4.y * w4.y + q4.z * w4.z + q4.w * w4.w;
    }
  }
  for (int b = 0; b < 64; ++b)
    u[((m * Bb + b) * Hh + h) * Kk + t] = acc[b];
  if (t < 64) {
    float s = 0.f;
#pragma unroll
    for (int d = 0; d < 32; ++d)
      s += qs[t * 36 + d] * bk[m * Kk + h * HD + d];
    qdb[(m * Bb + t) * Hh + h] = s;
  }
}

// ---------------------------------------------------------------------------
// K3 (fp16 MFMA, dbuf): scores(m,b,h,s) = (key·u + qdb)/sqrt(32)
__global__ __launch_bounds__(256) void k3_scores(
    const float* __restrict__ key, const float* __restrict__ u,
    const float* __restrict__ qdb, float* __restrict__ sc) {
  __shared__ unsigned Us[2][64 * 20];
  __shared__ unsigned Ks[2][64 * 20];
  __shared__ float qd[64];
  const int b = blockIdx.x, st0 = blockIdx.y * 64, t = threadIdx.x;
  const int w = t >> 6, lane = t & 63, quad = lane >> 4, l15 = lane & 15;
  if (t < 64) qd[t] = qdb[((t >> 3) * Bb + b) * Hh + (t & 7)];
  const int umh = t >> 2, ukg = t & 3;
  const float* ug =
      u + (((umh >> 3) * Bb + b) * Hh + (umh & 7)) * Kk + ukg * 8;
  const int ksr = t >> 2, kkg = t & 3;
  const float* kg =
      key + (size_t)(st0 + ksr) * (Bb * Kk) + b * Kk + kkg * 8;
  float4 pu[2][2], pkv[2][2];
  f32x4 acc[4];
#pragma unroll
  for (int i = 0; i < 4; ++i) acc[i] = (f32x4){0.f, 0.f, 0.f, 0.f};

#define K3_LOAD(c, s)                                   \
  {                                                     \
    pu[s][0] = *(const float4*)(ug + (c) * 32);         \
    pu[s][1] = *(const float4*)(ug + (c) * 32 + 4);     \
    pkv[s][0] = *(const float4*)(kg + (c) * 32);        \
    pkv[s][1] = *(const float4*)(kg + (c) * 32 + 4);    \
  }
#define K3_STORE(buf, s)                                                   \
  {                                                                        \
    uint4 v;                                                               \
    v.x = pk2(pu[s][0].x, pu[s][0].y); v.y = pk2(pu[s][0].z, pu[s][0].w);  \
    v.z = pk2(pu[s][1].x, pu[s][1].y); v.w = pk2(pu[s][1].z, pu[s][1].w);  \
    *(uint4*)&Us[buf][umh * 20 + ukg * 4] = v;                             \
    uint4 q_;                                                              \
    q_.x = pk2(pkv[s][0].x, pkv[s][0].y);                                  \
    q_.y = pk2(pkv[s][0].z, pkv[s][0].w);                                  \
    q_.z = pk2(pkv[s][1].x, pkv[s][1].y);                                  \
    q_.w = pk2(pkv[s][1].z, pkv[s][1].w);                                  \
    *(uint4*)&Ks[buf][ksr * 20 + kkg * 4] = q_;                            \
  }

  K3_LOAD(0, 0); K3_STORE(0, 0);
  K3_LOAD(1, 1);
#pragma unroll
  for (int c = 0; c < 8; ++c) {
    __syncthreads();
    if (c + 2 < 8) K3_LOAD(c + 2, c & 1);
    const f16x8 af = *(const f16x8*)&Us[c & 1][(w * 16 + l15) * 20 + quad * 4];
#pragma unroll
    for (int sf = 0; sf < 4; ++sf) {
      const f16x8 bf =
          *(const f16x8*)&Ks[c & 1][(sf * 16 + l15) * 20 + quad * 4];
      acc[sf] =
          __builtin_amdgcn_mfma_f32_16x16x32_f16(af, bf, acc[sf], 0, 0, 0);
    }
    if (c + 1 < 8) K3_STORE((c + 1) & 1, (c + 1) & 1);
  }
  const float scale = 0.17677669529663687f;  // 1/sqrt(32)
#pragma unroll
  for (int sf = 0; sf < 4; ++sf) {
    const int s = st0 + sf * 16 + l15;
#pragma unroll
    for (int r = 0; r < 4; ++r) {
      const int mh = w * 16 + quad * 4 + r;
      sc[(size_t)(((mh >> 3) * Bb + b) * Hh + (mh & 7)) * Ss + s] =
          (acc[sf][r] + qd[mh]) * scale;
    }
  }
#undef K3_LOAD
#undef K3_STORE
}

// ---------------------------------------------------------------------------
// K3b: softmax over s per (m,b,h) AND attn_weights mean-over-h, fused.
__global__ __launch_bounds__(256) void k3b_softmax(float* __restrict__ sc,
                                                   float* __restrict__ out) {
  __shared__ float rows[8 * 1024];
  const int m = blockIdx.x, b = blockIdx.y, t = threadIdx.x;
  const int w = t >> 6, lane = t & 63;
  const size_t base = (size_t)(m * Bb + b) * (Hh * Ss);
#pragma unroll
  for (int hh = 0; hh < 2; ++hh) {
    const int h = w * 2 + hh;
    float* g = sc + base + h * 1024;
    float4 v0 = *(const float4*)&g[lane * 4];
    float4 v1 = *(const float4*)&g[256 + lane * 4];
    float4 v2 = *(const float4*)&g[512 + lane * 4];
    float4 v3 = *(const float4*)&g[768 + lane * 4];
    float mx = fmaxf(fmaxf(fmaxf(v0.x, v0.y), fmaxf(v0.z, v0.w)),
                     fmaxf(fmaxf(v1.x, v1.y), fmaxf(v1.z, v1.w)));
    mx = fmaxf(mx, fmaxf(fmaxf(fmaxf(v2.x, v2.y), fmaxf(v2.z, v2.w)),
                         fmaxf(fmaxf(v3.x, v3.y), fmaxf(v3.z, v3.w))));
#pragma unroll
    for (int off = 32; off > 0; off >>= 1)
      mx = fmaxf(mx, __shfl_xor(mx, off, 64));
    v0.x = __expf(v0.x - mx); v0.y = __expf(v0.y - mx);
    v0.z = __expf(v0.z - mx); v0.w = __expf(v0.w - mx);
    v1.x = __expf(v1.x - mx); v1.y = __expf(v1.y - mx);
    v1.z = __expf(v1.z - mx); v1.w = __expf(v1.w - mx);
    v2.x = __expf(v2.x - mx); v2.y = __expf(v2.y - mx);
    v2.z = __expf(v2.z - mx); v2.w = __expf(v2.w - mx);
    v3.x = __expf(v3.x - mx); v3.y = __expf(v3.y - mx);
    v3.z = __expf(v3.z - mx); v3.w = __expf(v3.w - mx);
    float sm = v0.x + v0.y + v0.z + v0.w + v1.x + v1.y + v1.z + v1.w +
               v2.x + v2.y + v2.z + v2.w + v3.x + v3.y + v3.z + v3.w;
#pragma unroll
    for (int off = 32; off > 0; off >>= 1) sm += __shfl_xor(sm, off, 64);
    const float inv = 1.f / sm;
    v0.x *= inv; v0.y *= inv; v0.z *= inv; v0.w *= inv;
    v1.x *= inv; v1.y *= inv; v1.z *= inv; v1.w *= inv;
    v2.x *= inv; v2.y *= inv; v2.z *= inv; v2.w *= inv;
    v3.x *= inv; v3.y *= inv; v3.z *= inv; v3.w *= inv;
    *(float4*)&g[lane * 4] = v0;
    *(float4*)&g[256 + lane * 4] = v1;
    *(float4*)&g[512 + lane * 4] = v2;
    *(float4*)&g[768 + lane * 4] = v3;
    float* r = rows + h * 1024;
    *(float4*)&r[lane * 4] = v0;
    *(float4*)&r[256 + lane * 4] = v1;
    *(float4*)&r[512 + lane * 4] = v2;
    *(float4*)&r[768 + lane * 4] = v3;
  }
  __syncthreads();
#pragma unroll
  for (int p = 0; p < 4; ++p) {
    const int s = p * 256 + t;
    float sum = 0.f;
#pragma unroll
    for (int h = 0; h < 8; ++h) sum += rows[h * 1024 + s];
    out[131072u + (m * Bb + b) * Ss + s] = sum * 0.125f;
  }
}

// ---------------------------------------------------------------------------
// K4a (fp16 MFMA, dbuf): w(m,b,h,k) = sum_s aw(m,b,h,s)*value(s,b,k)
__global__ __launch_bounds__(256) void k4a_av(const float* __restrict__ value,
                                              const float* __restrict__ aw,
                                              float* __restrict__ wout) {
  __shared__ unsigned Ap[2][64 * 20];  // aw packed   [mh][sp]
  __shared__ unsigned Vp[2][32 * 20];  // value^T pk  [k][sp]
  const int b = blockIdx.x, ko = blockIdx.y, t = threadIdx.x;
  const int w = t >> 6, lane = t & 63, quad = lane >> 4, l15 = lane & 15;
  const int amh = t >> 2, asg = t & 3;
  const float* ag =
      aw + ((size_t)((amh >> 3) * Bb + b) * Hh + (amh & 7)) * Ss + asg * 8;
  const int vk = (t & 15) * 2, vsp = t >> 4;
  const float* vg = value + (size_t)(2 * vsp) * (Bb * Kk) + b * Kk +
                    ko * 32 + vk;
  const size_t srow = (size_t)(Bb * Kk);
  float4 pa[2][2];
  float2 pv[2][2];
  f32x4 acc[2];
  acc[0] = (f32x4){0.f, 0.f, 0.f, 0.f};
  acc[1] = (f32x4){0.f, 0.f, 0.f, 0.f};

#define K4_LOAD(c, s)                                         \
  {                                                           \
    pa[s][0] = *(const float4*)(ag + (c) * 32);               \
    pa[s][1] = *(const float4*)(ag + (c) * 32 + 4);           \
    const float* vb = vg + (size_t)(c) * 32 * srow;           \
    pv[s][0] = *(const float2*)vb;                            \
    pv[s][1] = *(const float2*)(vb + srow);                   \
  }
#define K4_STORE(buf, s)                                                   \
  {                                                                        \
    uint4 v;                                                               \
    v.x = pk2(pa[s][0].x, pa[s][0].y); v.y = pk2(pa[s][0].z, pa[s][0].w);  \
    v.z = pk2(pa[s][1].x, pa[s][1].y); v.w = pk2(pa[s][1].z, pa[s][1].w);  \
    *(uint4*)&Ap[buf][amh * 20 + asg * 4] = v;                             \
    Vp[buf][vk * 20 + vsp] = pk2(pv[s][0].x, pv[s][1].x);                  \
    Vp[buf][(vk + 1) * 20 + vsp] = pk2(pv[s][0].y, pv[s][1].y);            \
  }

  K4_LOAD(0, 0); K4_STORE(0, 0);
  K4_LOAD(1, 1);
#pragma unroll
  for (int c = 0; c < 32; ++c) {
    __syncthreads();
    if (c + 2 < 32) K4_LOAD(c + 2, c & 1);
    const f16x8 af = *(const f16x8*)&Ap[c & 1][(w * 16 + l15) * 20 + quad * 4];
#pragma unroll
    for (int nt = 0; nt < 2; ++nt) {
      const f16x8 bf =
          *(const f16x8*)&Vp[c & 1][(nt * 16 + l15) * 20 + quad * 4];
      acc[nt] =
          __builtin_amdgcn_mfma_f32_16x16x32_f16(af, bf, acc[nt], 0, 0, 0);
    }
    if (c + 1 < 32) K4_STORE((c + 1) & 1, (c + 1) & 1);
  }
#pragma unroll
  for (int nt = 0; nt < 2; ++nt) {
    const int k = ko * 32 + nt * 16 + l15;
#pragma unroll
    for (int r = 0; r < 4; ++r) {
      const int mh = w * 16 + quad * 4 + r;
      wout[((size_t)((mh >> 3) * Bb + b) * Hh + (mh & 7)) * Kk + k] =
          acc[nt][r];
    }
  }
#undef K4_LOAD
#undef K4_STORE
}

// ---------------------------------------------------------------------------
// K5: ctx = w @ Wv_h + bv ; attn_out = ctx @ Wo + bo ;
// fc_in = relu(concat) written as fp16 in MFMA A-frag layout:
//   fcp[(((m*16+kc)*64 + b)*4 + kj)*8 + ki], k = kc*32 + kj*8 + ki
__global__ __launch_bounds__(256) void k5_ctx(
    const float* __restrict__ wv, const float* __restrict__ bv,
    const float* __restrict__ wo, const float* __restrict__ bo,
    const float* __restrict__ s0in, const float* __restrict__ w,
    float* __restrict__ attn_out, _Float16* __restrict__ fcp) {
  __shared__ float wsh[2048];
  __shared__ float ctxs[256];
  const int m = blockIdx.x, b = blockIdx.y, t = threadIdx.x;
  const int base = (m * Bb + b) * (Hh * Kk);
#pragma unroll
  for (int p = 0; p < 8; ++p) wsh[p * 256 + t] = w[base + p * 256 + t];
  __syncthreads();
  const int h = t >> 5;
  float acc = bv[m * Kk + t];
  const float* wvc = wv + m * Kk * Kk + t;
  for (int k4 = 0; k4 < 64; ++k4) {
    const float4 a4 = *(const float4*)&wsh[h * 256 + k4 * 4];
    acc += a4.x * wvc[(k4 * 4 + 0) * Kk] + a4.y * wvc[(k4 * 4 + 1) * Kk] +
           a4.z * wvc[(k4 * 4 + 2) * Kk] + a4.w * wvc[(k4 * 4 + 3) * Kk];
  }
  ctxs[t] = acc;
  __syncthreads();
  float acc2 = bo[m * Kk + t];
  const float* woc = wo + m * Kk * Kk + t;
  for (int k4 = 0; k4 < 64; ++k4) {
    const float4 c4 = *(const float4*)&ctxs[k4 * 4];
    acc2 += c4.x * woc[(k4 * 4 + 0) * Kk] + c4.y * woc[(k4 * 4 + 1) * Kk] +
            c4.z * woc[(k4 * 4 + 2) * Kk] + c4.w * woc[(k4 * 4 + 3) * Kk];
  }
  const int ob = (m * Bb + b) * Kk + t;
  attn_out[ob] = acc2;
  {
    const float v1 = fmaxf(acc2, 0.f);        // k = t
    const float v2 = fmaxf(s0in[ob], 0.f);    // k = 256 + t
    const int kc1 = t >> 5, kj1 = (t >> 3) & 3, ki1 = t & 7;
    fcp[((size_t)((m * 16 + kc1) * 64 + b) * 4 + kj1) * 8 + ki1] =
        (_Float16)v1;
    const int k2i = 256 + t;
    const int kc2 = k2i >> 5, kj2 = (k2i >> 3) & 3, ki2 = k2i & 7;
    fcp[((size_t)((m * 16 + kc2) * 64 + b) * 4 + kj2) * 8 + ki2] =
        (_Float16)v2;
  }
}

// ---------------------------------------------------------------------------
// K6 (fp16 MFMA): h1[head] = relu(fc_in @ W1[head] + b1[head])
// A operand: direct global->VGPR dwordx4 from fcp (fp16 frag layout, no LDS).
// W operand: block-staged in LDS, 4 buffers, 3 rotating reg sets
// (load -> ds_write distance ~2-3 steps to cover HBM latency).
// Output: h1p fp16 in A-frag layout for k7a/k6b.
__global__ __launch_bounds__(256) void k6_mlp1(
    const _Float16* __restrict__ fcp, const float* __restrict__ w1q,
    const float* __restrict__ w1k, const float* __restrict__ w1v,
    const float* __restrict__ w1s, const float* __restrict__ w1g,
    const float* __restrict__ b1q, const float* __restrict__ b1k,
    const float* __restrict__ b1v, const float* __restrict__ b1s,
    const float* __restrict__ b1g, _Float16* __restrict__ h1p) {
  __shared__ unsigned Ws[4][16 * 68];  // W1^T packed [kp][f]
  const int ft = blockIdx.x, m = blockIdx.y, head = blockIdx.z,
            t = threadIdx.x;
  const float* w1;
  const float* b1;
  if (head == 0)      { w1 = w1q; b1 = b1q; }
  else if (head == 1) { w1 = w1k; b1 = b1k; }
  else if (head == 2) { w1 = w1v; b1 = b1v; }
  else if (head == 3) { w1 = w1s; b1 = b1s; }
  else {
    w1 = w1g + (size_t)(head - 4) * (Mm * 512 * Ff);
    b1 = b1g + (head - 4) * (Mm * Ff);
  }
  w1 += (size_t)m * 512 * Ff;
  b1 += m * Ff;
  const int w = t >> 6, lane = t & 63, quad = lane >> 4, l15 = lane & 15;
  const int wf0 = (t & 15) * 4, wkp = t >> 4;
  const float* wg = w1 + (size_t)(2 * wkp) * Ff + ft * 64 + wf0;
  // A-frag base: lane l -> fc[b = mt*16+l15][k = c*32 + quad*8 .. +8]
  const _Float16* ag = fcp + ((size_t)(m * 16) * 64 + l15) * 32 + quad * 8;
  float4 pw[3][2];
  f16x8 av[2][4];
  f32x4 acc[4];
#pragma unroll
  for (int i = 0; i < 4; ++i) acc[i] = (f32x4){0.f, 0.f, 0.f, 0.f};

#define K6_WLOAD(c, s)                                           \
  {                                                              \
    const float* wb = wg + (size_t)(c) * 32 * Ff;                \
    pw[s][0] = *(const float4*)wb;                               \
    pw[s][1] = *(const float4*)(wb + Ff);                        \
  }
#define K6_ALOAD(c, s)                                           \
  {                                                              \
    const _Float16* ab = ag + (size_t)(c) * 2048;                \
    av[s][0] = *(const f16x8*)(ab);                              \
    av[s][1] = *(const f16x8*)(ab + 512);                        \
    av[s][2] = *(const f16x8*)(ab + 1024);                       \
    av[s][3] = *(const f16x8*)(ab + 1536);                       \
  }
#define K6_WSTORE(buf, s)                                                  \
  {                                                                        \
    uint4 wv_;                                                             \
    wv_.x = pk2(pw[s][0].x, pw[s][1].x);                                   \
    wv_.y = pk2(pw[s][0].y, pw[s][1].y);                                   \
    wv_.z = pk2(pw[s][0].z, pw[s][1].z);                                   \
    wv_.w = pk2(pw[s][0].w, pw[s][1].w);                                   \
    *(uint4*)&Ws[buf][wkp * 68 + wf0] = wv_;                               \
  }

  // Prologue: chunk k lives in reg set k%3, LDS buffer k&3.
  K6_WLOAD(0, 0); K6_WSTORE(0, 0);
  K6_WLOAD(1, 1);
  K6_WLOAD(2, 2);
  K6_ALOAD(0, 0);
#pragma unroll
  for (int c = 0; c < 16; ++c) {
    __syncthreads();
    if (c + 3 < 16) K6_WLOAD(c + 3, c % 3);
    if (c + 1 < 16) K6_ALOAD(c + 1, (c + 1) & 1);
    union { f16x8 v; unsigned u[4]; } bfu;
#pragma unroll
    for (int j = 0; j < 4; ++j)
      bfu.u[j] = Ws[c & 3][(quad * 4 + j) * 68 + w * 16 + l15];
    const f16x8 bf = bfu.v;
#pragma unroll
    for (int mt = 0; mt < 4; ++mt)
      acc[mt] = __builtin_amdgcn_mfma_f32_16x16x32_f16(av[c & 1][mt], bf,
                                                       acc[mt], 0, 0, 0);
    if (c + 1 < 16) K6_WSTORE((c + 1) & 3, (c + 1) % 3);
  }
  const int f = ft * 64 + w * 16 + l15;
  const float bias = b1[f];
  // h1p frag layout: [(hm*32+kc)*64 + b]*32 + kj*8 + ki, f = kc*32+kj*8+ki
  _Float16* hb = h1p +
      (size_t)((head * Mm + m) * 32 + ft * 2 + (w >> 1)) * 2048 +
      ((w & 1) * 2 + (l15 >> 3)) * 8 + (l15 & 7);
#pragma unroll
  for (int mt = 0; mt < 4; ++mt) {
#pragma unroll
    for (int r = 0; r < 4; ++r) {
      const int bb = mt * 16 + quad * 4 + r;
      hb[(size_t)bb * 32] = (_Float16)fmaxf(acc[mt][r] + bias, 0.f);
    }
  }
#undef K6_WLOAD
#undef K6_ALOAD
#undef K6_WSTORE
}

// ---------------------------------------------------------------------------
// K6b: gates(g,m,b) = sigmoid(h1[4+g,m,b,:] . g_w2[g,m,:] + g_b2[g,m])
// h1p is fp16 frag layout; summation order is free, so walk it linearly.
__global__ __launch_bounds__(64) void k6b_gates(
    const _Float16* __restrict__ h1p, const float* __restrict__ gw2,
    const float* __restrict__ gb2, float* __restrict__ gates) {
  const int gm = blockIdx.x, b = blockIdx.y, t = threadIdx.x;
  const int g = gm >> 3, m = gm & 7;
  const _Float16* hrow =
      h1p + (size_t)((4 + g) * Mm + m) * 65536 + (size_t)b * 32;
  const float* wrow = gw2 + (g * Mm + m) * Ff;
  float s = 0.f;
#pragma unroll
  for (int i = 0; i < 2; ++i) {
    const int G = t + i * 64;           // G = kc*4 + kj, f0 = G*8
    const int kc = G >> 2, kj = G & 3;
    const f16x8 hv = *(const f16x8*)(hrow + (size_t)kc * 2048 + kj * 8);
    const float4 wa = *(const float4*)(wrow + G * 8);
    const float4 wb = *(const float4*)(wrow + G * 8 + 4);
    s += (float)hv[0] * wa.x + (float)hv[1] * wa.y + (float)hv[2] * wa.z +
         (float)hv[3] * wa.w + (float)hv[4] * wb.x + (float)hv[5] * wb.y +
         (float)hv[6] * wb.z + (float)hv[7] * wb.w;
  }
  for (int off = 32; off > 0; off >>= 1) s += __shfl_down(s, off, 64);
  if (t == 0)
    gates[(g * Mm + m) * Bb + b] =
        1.f / (1.f + __expf(-(s + gb2[g * Mm + m])));
}

// ---------------------------------------------------------------------------
// K7a (fp16 MFMA): partial head outputs, k-split 4 over f.
// Same structure as k6: A direct from h1p (fp16 frag layout), W-only LDS
// staging with 4 buffers / 3 reg sets.
__global__ __launch_bounds__(256) void k7a_mlp2(
    const _Float16* __restrict__ h1p, const float* __restrict__ w2q,
    const float* __restrict__ w2k, const float* __restrict__ w2v,
    const float* __restrict__ w2s, float* __restrict__ hpart) {
  __shared__ unsigned Ws[4][16 * 68];  // w2^T packed [fp][o]
  const int ot = blockIdx.x & 3, fq = blockIdx.x >> 2;
  const int m = blockIdx.y, head = blockIdx.z, t = threadIdx.x;
  const float* w2 =
      (head == 0) ? w2q : (head == 1) ? w2k : (head == 2) ? w2v : w2s;
  w2 += (size_t)m * Ff * Kk;
  const int w = t >> 6, lane = t & 63, quad = lane >> 4, l15 = lane & 15;
  const int wf0 = (t & 15) * 4, wkp = t >> 4;
  const float* wg = w2 + (size_t)(fq * 256 + 2 * wkp) * Kk + ot * 64 + wf0;
  const _Float16* ag = h1p +
      (size_t)((head * Mm + m) * 32 + fq * 8) * 2048 + (size_t)l15 * 32 +
      quad * 8;
  float4 pw[3][2];
  f16x8 av[2][4];
  f32x4 acc[4];
#pragma unroll
  for (int i = 0; i < 4; ++i) acc[i] = (f32x4){0.f, 0.f, 0.f, 0.f};

#define K7_WLOAD(c, s)                                           \
  {                                                              \
    const float* wb = wg + (size_t)(c) * 32 * Kk;                \
    pw[s][0] = *(const float4*)wb;                               \
    pw[s][1] = *(const float4*)(wb + Kk);                        \
  }
#define K7_ALOAD(c, s)                                           \
  {                                                              \
    const _Float16* ab = ag + (size_t)(c) * 2048;                \
    av[s][0] = *(const f16x8*)(ab);                              \
    av[s][1] = *(const f16x8*)(ab + 512);                        \
    av[s][2] = *(const f16x8*)(ab + 1024);                       \
    av[s][3] = *(const f16x8*)(ab + 1536);                       \
  }
#define K7_WSTORE(buf, s)                                                  \
  {                                                                        \
    uint4 wv_;                                                             \
    wv_.x = pk2(pw[s][0].x, pw[s][1].x);                                   \
    wv_.y = pk2(pw[s][0].y, pw[s][1].y);                                   \
    wv_.z = pk2(pw[s][0].z, pw[s][1].z);                                   \
    wv_.w = pk2(pw[s][0].w, pw[s][1].w);                                   \
    *(uint4*)&Ws[buf][wkp * 68 + wf0] = wv_;                               \
  }

  K7_WLOAD(0, 0); K7_WSTORE(0, 0);
  K7_WLOAD(1, 1);
  K7_WLOAD(2, 2);
  K7_ALOAD(0, 0);
#pragma unroll
  for (int c = 0; c < 8; ++c) {
    __syncthreads();
    if (c + 3 < 8) K7_WLOAD(c + 3, c % 3);
    if (c + 1 < 8) K7_ALOAD(c + 1, (c + 1) & 1);
    union { f16x8 v; unsigned u[4]; } bfu;
#pragma unroll
    for (int j = 0; j < 4; ++j)
      bfu.u[j] = Ws[c & 3][(quad * 4 + j) * 68 + w * 16 + l15];
    const f16x8 bf = bfu.v;
#pragma unroll
    for (int mt = 0; mt < 4; ++mt)
      acc[mt] = __builtin_amdgcn_mfma_f32_16x16x32_f16(av[c & 1][mt], bf,
                                                       acc[mt], 0, 0, 0);
    if (c + 1 < 8) K7_WSTORE((c + 1) & 3, (c + 1) % 3);
  }
  const int o = ot * 64 + w * 16 + l15;
  float* hp =
      hpart + fq * 524288u + (size_t)((head * Mm + m) * Bb) * Kk + o;
#pragma unroll
  for (int mt = 0; mt < 4; ++mt) {
#pragma unroll
    for (int r = 0; r < 4; ++r) {
      const int bb = mt * 16 + quad * 4 + r;
      hp[(size_t)bb * Kk] = acc[mt][r];
    }
  }
#undef K7_WLOAD
#undef K7_ALOAD
#undef K7_WSTORE
}

// ---------------------------------------------------------------------------
// K7b: out = gate*tanh(relu(p0+p1+p2+p3+b2)) + (1-gate)*x0
__global__ __launch_bounds__(256) void k7b_final(
    const float* __restrict__ hpart, const float* __restrict__ gates,
    const float* __restrict__ b2q, const float* __restrict__ b2k,
    const float* __restrict__ b2v, const float* __restrict__ b2s,
    const float* __restrict__ q0, const float* __restrict__ k0,
    const float* __restrict__ v0, const float* __restrict__ s0,
    float* __restrict__ out) {
  const int idx = blockIdx.x * 256 + threadIdx.x;
  const int o = idx & 255;
  const int b = (idx >> 8) & 63;
  const int m = (idx >> 14) & 7;
  const int head = idx >> 17;
  const float* b2 = (head == 0) ? b2q : (head == 1) ? b2k
                    : (head == 2) ? b2v : b2s;
  const float* x0 = (head == 0) ? q0 : (head == 1) ? k0
                    : (head == 2) ? v0 : s0;
  const unsigned ooff = (head == 0) ? 786432u
                        : (head == 1) ? 917504u
                        : (head == 2) ? 1048576u : 655360u;
  float v = hpart[idx] + hpart[524288u + idx] + hpart[1048576u + idx] +
            hpart[1572864u + idx] + b2[m * Kk + o];
  v = tanhf(fmaxf(v, 0.f));
  const float g = gates[(head * Mm + m) * Bb + b];
  const float x = x0[(m * Bb + b) * Kk + o];
  out[ooff + (m * Bb + b) * Kk + o] = g * v + (1.f - g) * x;
}

// ---------------------------------------------------------------------------
extern "C" void kernel_launch(void* const* d_in, const int* in_sizes, int n_in,
                              void* d_out, int out_size, void* d_ws,
                              size_t ws_size, hipStream_t stream) {
  (void)in_sizes; (void)n_in; (void)out_size; (void)ws_size;
  const float* s0  = (const float*)d_in[0];
  const float* q0  = (const float*)d_in[1];
  const float* k0  = (const float*)d_in[2];
  const float* v0  = (const float*)d_in[3];
  const float* key = (const float*)d_in[4];
  const float* val = (const float*)d_in[5];
  const float* wq  = (const float*)d_in[6];
  const float* wk  = (const float*)d_in[7];
  const float* wv  = (const float*)d_in[8];
  const float* bqa = (const float*)d_in[9];
  const float* bka = (const float*)d_in[10];
  const float* bva = (const float*)d_in[11];
  const float* wo  = (const float*)d_in[12];
  const float* bo  = (const float*)d_in[13];
  const float* qw1 = (const float*)d_in[14];
  const float* qb1 = (const float*)d_in[15];
  const float* qw2 = (const float*)d_in[16];
  const float* qb2 = (const float*)d_in[17];
  const float* kw1 = (const float*)d_in[18];
  const float* kb1 = (const float*)d_in[19];
  const float* kw2 = (const float*)d_in[20];
  const float* kb2 = (const float*)d_in[21];
  const float* vw1 = (const float*)d_in[22];
  const float* vb1 = (const float*)d_in[23];
  const float* vw2 = (const float*)d_in[24];
  const float* vb2 = (const float*)d_in[25];
  const float* sw1 = (const float*)d_in[26];
  const float* sb1 = (const float*)d_in[27];
  const float* sw2 = (const float*)d_in[28];
  const float* sb2 = (const float*)d_in[29];
  const float* gw1 = (const float*)d_in[30];
  const float* gb1 = (const float*)d_in[31];
  const float* gw2 = (const float*)d_in[32];
  const float* gb2 = (const float*)d_in[33];
  float* ws  = (float*)d_ws;
  float* out = (float*)d_out;

  k1_qproj<<<dim3(8, 8), 256, 0, stream>>>(q0, wq, bqa, ws + WS_Q);
  k2_uproj<<<dim3(8, 8), 256, 0, stream>>>(wk, bka, ws + WS_Q, ws + WS_U,
                                           ws + WS_QDB);
  k3_scores<<<dim3(64, 16), 256, 0, stream>>>(key, ws + WS_U, ws + WS_QDB,
                                              ws + WS_SC);
  k3b_softmax<<<dim3(8, 64), 256, 0, stream>>>(ws + WS_SC, out);
  k4a_av<<<dim3(64, 8), 256, 0, stream>>>(val, ws + WS_SC, ws + WS_W);
  k5_ctx<<<dim3(8, 64), 256, 0, stream>>>(wv, bva, wo, bo, s0, ws + WS_W, out,
                                          (_Float16*)(ws + WS_FCP));
  k6_mlp1<<<dim3(16, 8, 8), 256, 0, stream>>>(
      (const _Float16*)(ws + WS_FCP), qw1, kw1, vw1, sw1, gw1, qb1, kb1, vb1,
      sb1, gb1, (_Float16*)(ws + WS_H1P));
  k6b_gates<<<dim3(32, 64), 64, 0, stream>>>(
      (const _Float16*)(ws + WS_H1P), gw2, gb2, ws + WS_GATES);
  k7a_mlp2<<<dim3(16, 8, 4), 256, 0, stream>>>(
      (const _Float16*)(ws + WS_H1P), qw2, kw2, vw2, sw2, ws + WS_HPART);
  k7b_final<<<dim3(2048), 256, 0, stream>>>(ws + WS_HPART, ws + WS_GATES, qb2,
                                            kb2, vb2, sb2, q0, k0, v0, s0,
                                            out);
}